// Round 6
// baseline (1866.586 us; speedup 1.0000x reference)
//
#include <hip/hip_runtime.h>

#define T_TOK 4096
#define HID   4096
#define IMD   11008

using f32x4  = __attribute__((ext_vector_type(4))) float;
using bf16x8 = __attribute__((ext_vector_type(8))) __bf16;
union FragCast { int4 i; bf16x8 b; };

__device__ __forceinline__ unsigned f2bf_bits(float f) {
  unsigned u = __float_as_uint(f);
  return (u + 0x7fffu + ((u >> 16) & 1u)) >> 16;   // RNE f32 -> bf16
}
__device__ __forceinline__ float bf2f(short s) {
  return __uint_as_float(((unsigned)(unsigned short)s) << 16);
}
__device__ __forceinline__ int4 cvt8(const float4 f0, const float4 f1) {
  int4 r;
  r.x = f2bf_bits(f0.x) | (f2bf_bits(f0.y) << 16);
  r.y = f2bf_bits(f0.z) | (f2bf_bits(f0.w) << 16);
  r.z = f2bf_bits(f1.x) | (f2bf_bits(f1.y) << 16);
  r.w = f2bf_bits(f1.z) | (f2bf_bits(f1.w) << 16);
  return r;
}
__device__ __forceinline__ void gload16(const void* g, void* l) {
  __builtin_amdgcn_global_load_lds(
      (__attribute__((address_space(1))) void*)g,
      (__attribute__((address_space(3))) void*)l, 16, 0, 0);
}

// ---------------------------------------------------------------- prep kernels
__global__ void cvt_pad(const float* __restrict__ in, short* __restrict__ out,
                        int C8, long ldin, long ldout) {
  long r = blockIdx.x;
  const float4* s = (const float4*)(in + r * ldin);
  int4* d = (int4*)(out + r * ldout);
  for (int c = threadIdx.x; c < C8; c += blockDim.x)
    d[c] = cvt8(s[2 * c], s[2 * c + 1]);
}

__global__ void build_wbT_pad(const float* __restrict__ wb,
                              short* __restrict__ out, int N, long ldout,
                              long K) {
  int n = blockIdx.x * blockDim.x + threadIdx.x;
  int ar = blockIdx.y;
  if (n < N) out[(long)n * ldout + K + ar] = (short)f2bf_bits(wb[(long)ar * N + n]);
}

__global__ void tail_copy(const short* __restrict__ src, short* dst, long ld) {
  dst[(long)blockIdx.x * ld + threadIdx.x] = src[blockIdx.x * 64 + threadIdx.x];
}

// per-token rank projection: out[t][a*16+r] = mask * sum_h Abf[t][h]*wa[a][h][r]
template <int KD, int NOUT>
__global__ __launch_bounds__(256)
void lora_proj(const short* __restrict__ Abf, long ldA,
               const float* __restrict__ wa0, const float* __restrict__ wa1,
               const int* __restrict__ seg, short* out0, long ld0, short* out1,
               long ld1) {
  __shared__ __align__(16) short rowbuf[KD];
  __shared__ float part[NOUT][4][16];
  int t = blockIdx.x, tid = threadIdx.x;
  int a = seg[t];
  const int4* src = (const int4*)(Abf + (long)t * ldA);
  for (int c = tid; c < KD / 8; c += 256) ((int4*)rowbuf)[c] = src[c];
  __syncthreads();
  int w = tid >> 6, l = tid & 63;
  int r = l & 15, g = l >> 4;
  const int HW = KD / 4;
  float s0 = 0.f, s1 = 0.f;
  const float* p0 = wa0 + (long)a * KD * 16 + r;
  const float* p1 = (NOUT == 2) ? (wa1 + (long)a * KD * 16 + r) : nullptr;
  int h = w * HW + g;
  for (int k = 0; k < HW / 4; ++k, h += 4) {
    float xv = bf2f(rowbuf[h]);
    s0 = fmaf(xv, p0[(long)h * 16], s0);
    if (NOUT == 2) s1 = fmaf(xv, p1[(long)h * 16], s1);
  }
  s0 += __shfl_xor(s0, 16); s0 += __shfl_xor(s0, 32);
  if (NOUT == 2) { s1 += __shfl_xor(s1, 16); s1 += __shfl_xor(s1, 32); }
  if (l < 16) { part[0][w][r] = s0; if (NOUT == 2) part[1][w][r] = s1; }
  __syncthreads();
  if (tid < 64 * NOUT) {
    int m = tid >> 6, ar = tid & 63;
    float v = 0.f;
    if ((ar >> 4) == a) {
      int r2 = ar & 15;
      v = part[m][0][r2] + part[m][1][r2] + part[m][2][r2] + part[m][3][r2];
    }
    short b = (short)f2bf_bits(v);
    if (m == 0) out0[(long)t * ld0 + ar] = b;
    else        out1[(long)t * ld1 + ar] = b;
  }
}

// ------------------- GEMM: 256x256, 1-barrier/K-step pipelined schedule
// C[M][N] = A[M][ldK]@B[N][ldK]^T (LoRA folded as padded K-tail). BM=BN=256,
// BK=64, 512 thr = 8 waves (2M x 4N), per-wave 128x64. A triple-, B double-
// buffered (160KB LDS). Per K-step (64 MFMA per wave between barriers):
//   p0: stage B(t+1)h0 | read aF23(t) | cluster0 (aF01 x bF, 16 MFMA)
//   p1: stage B(t+1)h1 | read aF45(t) | cluster1
//   p2: stage A(t+2)h0 | read aF67(t) | cluster2
//   p3: stage A(t+2)h1 | cluster3 | vmcnt(4) | s_barrier |
//       read bF(t+1), aF01(t+1)          <- pipelined for next step
// Frag reads run one cluster ahead -> each cluster's lgkm wait is covered by
// the previous cluster's MFMA; waves skew freely within the K-step so MFMA
// overlaps other waves' ds_read/stage (fine interleave, T3+T4).
// vmcnt(4) proof: wave-local queue at the wait (oldest->newest) =
// [A(t+1)h1(2)?, B(t+1)(4), A(t+2)(4)]; leaving 4 -> A(t+1),B(t+1) landed,
// A(t+2) still in flight. Never drains mid-loop.
// WAR: reads of a buffer and its overwrite are separated by >=1 collective
// barrier (B buf: read after bar(t), rewritten after bar(t+1); A ring same).
// LDS XOR-swizzle source-side (rule #21): linear gload dest, global chunk
// c8^(row&7), read chunk x^(lrow&7). Zero conflicts (R2-R5 measured).
template <int MODE>  // 0: bf16 store; 1: silu(gbuf)*acc -> bf16 in-place; 2: f32
__global__ __launch_bounds__(512, 2)
void gemm256(const short* __restrict__ A, const short* __restrict__ B,
             const short* gbuf, short* outB, float* outF, int nby, long ldK,
             int iters, long ldo) {
  extern __shared__ __align__(16) char smem[];
  // A bufs: 3 x 32KB at 0; B bufs: 2 x 32KB at 98304.

  int nwg = gridDim.x;
  int orig = blockIdx.x;
  int q = nwg >> 3, rr = nwg & 7;
  int xcd = orig & 7, loc = orig >> 3;
  int swz = (xcd < rr ? xcd * (q + 1) : rr * (q + 1) + (xcd - rr) * q) + loc;
  int by = swz % nby, bx = swz / nby;   // col fastest: A panel stays in L2
  long row0 = (long)bx * 256, col0 = (long)by * 256;

  int tid = threadIdx.x;
  int l = tid & 63, wid = tid >> 6;
  int wr = wid >> 2, wc = wid & 3;      // 2M x 4N waves, 128x64 each
  int lrow = l & 15, lhi = l >> 4, md = lrow & 7;

  const short* aP[4]; const short* bP[4];
#pragma unroll
  for (int k = 0; k < 4; ++k) {
    int idx = tid + k * 512;
    int r = idx >> 3, c8 = idx & 7;
    aP[k] = A + (row0 + r) * ldK + (c8 ^ (r & 7)) * 8;
    bP[k] = B + (col0 + r) * ldK + (c8 ^ (r & 7)) * 8;
  }
  char* dbase = smem + tid * 16;   // + k*8192 (imm) selects the load's chunk

  auto stageA_h = [&](int bi, int h) {
    char* d = dbase + bi * 32768;
    gload16(aP[2 * h], d + (2 * h) * 8192);         aP[2 * h] += 64;
    gload16(aP[2 * h + 1], d + (2 * h + 1) * 8192); aP[2 * h + 1] += 64;
  };
  auto stageB_h = [&](int bi, int h) {
    char* d = dbase + 98304 + bi * 32768;
    gload16(bP[2 * h], d + (2 * h) * 8192);         bP[2 * h] += 64;
    gload16(bP[2 * h + 1], d + (2 * h + 1) * 8192); bP[2 * h + 1] += 64;
  };

  f32x4 acc[8][4];
  f32x4 zr = {0.f, 0.f, 0.f, 0.f};
#pragma unroll
  for (int mi = 0; mi < 8; ++mi)
#pragma unroll
    for (int ni = 0; ni < 4; ++ni) acc[mi][ni] = zr;

  const int csel0 = (lhi ^ md) * 16;
  const int csel1 = ((4 + lhi) ^ md) * 16;

  bf16x8 bF[4][2], aF01[2][2], aF23[2][2], aF45[2][2], aF67[2][2];

  auto readA = [&](const char* Ab, int mseg, bf16x8 (&aF)[2][2]) {
#pragma unroll
    for (int m2 = 0; m2 < 2; ++m2) {
      const char* base = Ab + (wr * 128 + mseg * 32 + m2 * 16 + lrow) * 128;
      FragCast f0, f1;
      f0.i = *(const int4*)(base + csel0);
      f1.i = *(const int4*)(base + csel1);
      aF[m2][0] = f0.b; aF[m2][1] = f1.b;
    }
  };
  auto readB = [&](const char* Bb) {
#pragma unroll
    for (int ni = 0; ni < 4; ++ni) {
      const char* base = Bb + (wc * 64 + ni * 16 + lrow) * 128;
      FragCast f0, f1;
      f0.i = *(const int4*)(base + csel0);
      f1.i = *(const int4*)(base + csel1);
      bF[ni][0] = f0.b; bF[ni][1] = f1.b;
    }
  };
  auto cluster = [&](int p, bf16x8 (&aF)[2][2]) {
    __builtin_amdgcn_s_setprio(1);
#pragma unroll
    for (int k = 0; k < 2; ++k)
#pragma unroll
      for (int m2 = 0; m2 < 2; ++m2)
#pragma unroll
        for (int ni = 0; ni < 4; ++ni)
          acc[p * 2 + m2][ni] = __builtin_amdgcn_mfma_f32_16x16x32_bf16(
              aF[m2][k], bF[ni][k], acc[p * 2 + m2][ni], 0, 0, 0);
    __builtin_amdgcn_s_setprio(0);
  };

  // prologue: A(0), B(0), A(1); confirm A(0),B(0); A(1) stays in flight
  stageA_h(0, 0); stageA_h(0, 1);
  stageB_h(0, 0); stageB_h(0, 1);
  stageA_h(1, 0); stageA_h(1, 1);
  asm volatile("s_waitcnt vmcnt(4)" ::: "memory");
  __builtin_amdgcn_s_barrier();
  readB(smem + 98304);
  readA(smem, 0, aF01);

  int ca = 0;                             // A buffer holding A(t)
#pragma unroll 1
  for (int t = 0; t < iters; ++t) {
    const char* Ab = smem + ca * 32768;
    int na2 = (ca >= 1) ? ca - 1 : 2;     // (ca+2)%3: buffer for A(t+2)
    int nb1 = (t + 1) & 1;
    // p0
    if (t + 1 < iters) stageB_h(nb1, 0);
    readA(Ab, 1, aF23);
    cluster(0, aF01);
    // p1
    if (t + 1 < iters) stageB_h(nb1, 1);
    readA(Ab, 2, aF45);
    cluster(1, aF23);
    // p2
    if (t + 2 < iters) stageA_h(na2, 0);
    readA(Ab, 3, aF67);
    cluster(2, aF45);
    // p3
    if (t + 2 < iters) stageA_h(na2, 1);
    cluster(3, aF67);
    if (t + 2 < iters)      asm volatile("s_waitcnt vmcnt(4)" ::: "memory");
    else if (t + 1 < iters) asm volatile("s_waitcnt vmcnt(0)" ::: "memory");
    if (t + 1 < iters) {
      __builtin_amdgcn_s_barrier();
      readB(smem + 98304 + nb1 * 32768);
      readA(smem + ((ca < 2) ? ca + 1 : 0) * 32768, 0, aF01);
    }
    ca = (ca < 2) ? ca + 1 : 0;
  }

  // epilogue: C/D layout col=lane&15, row=(lane>>4)*4+reg  [m89]
#pragma unroll
  for (int mi = 0; mi < 8; ++mi)
#pragma unroll
    for (int ni = 0; ni < 4; ++ni)
#pragma unroll
      for (int j = 0; j < 4; ++j) {
        long grow = row0 + wr * 128 + mi * 16 + lhi * 4 + j;
        long gcol = col0 + wc * 64 + ni * 16 + lrow;
        long idx = grow * ldo + gcol;
        float v = acc[mi][ni][j];
        if constexpr (MODE == 0) {
          outB[idx] = (short)f2bf_bits(v);
        } else if constexpr (MODE == 1) {
          float g = bf2f(gbuf[idx]);
          float t2 = g * (1.f / (1.f + __expf(-g))) * v;   // silu(g)*u
          outB[idx] = (short)f2bf_bits(t2);
        } else {
          outF[idx] = v;
        }
      }
}

// ---------------------------------------------------------------- launcher
extern "C" void kernel_launch(void* const* d_in, const int* in_sizes, int n_in,
                              void* d_out, int out_size, void* d_ws,
                              size_t ws_size, hipStream_t stream) {
  const float* x       = (const float*)d_in[0];
  const float* gate_w  = (const float*)d_in[1];
  const float* up_w    = (const float*)d_in[2];
  const float* down_w  = (const float*)d_in[3];
  const float* gate_wa = (const float*)d_in[4];
  const float* gate_wb = (const float*)d_in[5];
  const float* up_wa   = (const float*)d_in[6];
  const float* up_wb   = (const float*)d_in[7];
  const float* down_wa = (const float*)d_in[8];
  const float* down_wb = (const float*)d_in[9];
  const int*   seg     = (const int*)d_in[10];

  char* ws = (char*)d_ws;
  short* xg_pad = (short*)(ws);                   // [4096][4160]  34.1 MB
  short* wA     = (short*)(ws + 34078720);        // gate_w pad -> down_w pad
  short* wB     = (short*)(ws + 125665280);       // up_w pad      91.6 MB
  short* t_pad  = (short*)(ws + 217251840);       // [4096][11072] 90.7 MB
  short* xa_u   = (short*)(ws + 307953664);       // [4096][64]

  const int LDS_BYTES = 163840;   // 3 x 32KB A + 2 x 32KB B
  hipFuncSetAttribute(reinterpret_cast<const void*>(&gemm256<0>),
                      hipFuncAttributeMaxDynamicSharedMemorySize, LDS_BYTES);
  hipFuncSetAttribute(reinterpret_cast<const void*>(&gemm256<1>),
                      hipFuncAttributeMaxDynamicSharedMemorySize, LDS_BYTES);
  hipFuncSetAttribute(reinterpret_cast<const void*>(&gemm256<2>),
                      hipFuncAttributeMaxDynamicSharedMemorySize, LDS_BYTES);

  // bf16 padded operand build
  cvt_pad<<<T_TOK, 256, 0, stream>>>(x, xg_pad, 512, HID, 4160);
  cvt_pad<<<IMD, 256, 0, stream>>>(gate_w, wA, 512, HID, 4160);
  cvt_pad<<<IMD, 256, 0, stream>>>(up_w, wB, 512, HID, 4160);
  build_wbT_pad<<<dim3(43, 64), 256, 0, stream>>>(gate_wb, wA, IMD, 4160, HID);
  build_wbT_pad<<<dim3(43, 64), 256, 0, stream>>>(up_wb, wB, IMD, 4160, HID);
  lora_proj<HID, 2><<<T_TOK, 256, 0, stream>>>(
      xg_pad, 4160, gate_wa, up_wa, seg, xg_pad + HID, 4160, xa_u, 64);

  // gate: t_pad = x @ gate_w^T + lora        [M=4096, N=11008, K'=4160]
  gemm256<0><<<16 * 43, 512, LDS_BYTES, stream>>>(
      xg_pad, wA, nullptr, t_pad, nullptr, 43, 4160, 65, 11072);
  // swap LoRA tail to up's xa, then up+silu fuse (in place over t_pad)
  tail_copy<<<T_TOK, 64, 0, stream>>>(xa_u, xg_pad + HID, 4160);
  gemm256<1><<<16 * 43, 512, LDS_BYTES, stream>>>(
      xg_pad, wB, t_pad, t_pad, nullptr, 43, 4160, 65, 11072);

  // down operand build (wA region is free after gate GEMM)
  cvt_pad<<<T_TOK, 256, 0, stream>>>(down_w, wA, 1376, IMD, 11072);
  build_wbT_pad<<<dim3(16, 64), 256, 0, stream>>>(down_wb, wA, HID, 11072, IMD);
  lora_proj<IMD, 1><<<T_TOK, 256, 0, stream>>>(
      t_pad, 11072, down_wa, nullptr, seg, t_pad + IMD, 11072, nullptr, 64);

  // down: out = t @ down_w^T + lora          [M=4096, N=4096, K'=11072]
  gemm256<2><<<16 * 16, 512, LDS_BYTES, stream>>>(
      t_pad, wA, nullptr, nullptr, (float*)d_out, 16, 11072, 173, 4096);
}

// Round 7
// 1854.626 us; speedup vs baseline: 1.0064x; 1.0064x over previous
//
#include <hip/hip_runtime.h>

#define T_TOK 4096
#define HID   4096
#define IMD   11008

using f32x4  = __attribute__((ext_vector_type(4))) float;
using bf16x8 = __attribute__((ext_vector_type(8))) __bf16;
union FragCast { int4 i; bf16x8 b; };

__device__ __forceinline__ unsigned f2bf_bits(float f) {
  unsigned u = __float_as_uint(f);
  return (u + 0x7fffu + ((u >> 16) & 1u)) >> 16;   // RNE f32 -> bf16
}
__device__ __forceinline__ float bf2f(short s) {
  return __uint_as_float(((unsigned)(unsigned short)s) << 16);
}
__device__ __forceinline__ int4 cvt8(const float4 f0, const float4 f1) {
  int4 r;
  r.x = f2bf_bits(f0.x) | (f2bf_bits(f0.y) << 16);
  r.y = f2bf_bits(f0.z) | (f2bf_bits(f0.w) << 16);
  r.z = f2bf_bits(f1.x) | (f2bf_bits(f1.y) << 16);
  r.w = f2bf_bits(f1.z) | (f2bf_bits(f1.w) << 16);
  return r;
}
__device__ __forceinline__ void gload16(const void* g, void* l) {
  __builtin_amdgcn_global_load_lds(
      (__attribute__((address_space(1))) void*)g,
      (__attribute__((address_space(3))) void*)l, 16, 0, 0);
}

// ---------------------------------------------------------------- prep kernels
__global__ void cvt_pad(const float* __restrict__ in, short* __restrict__ out,
                        int C8, long ldin, long ldout) {
  long r = blockIdx.x;
  const float4* s = (const float4*)(in + r * ldin);
  int4* d = (int4*)(out + r * ldout);
  for (int c = threadIdx.x; c < C8; c += blockDim.x)
    d[c] = cvt8(s[2 * c], s[2 * c + 1]);
}

__global__ void build_wbT_pad(const float* __restrict__ wb,
                              short* __restrict__ out, int N, long ldout,
                              long K) {
  int n = blockIdx.x * blockDim.x + threadIdx.x;
  int ar = blockIdx.y;
  if (n < N) out[(long)n * ldout + K + ar] = (short)f2bf_bits(wb[(long)ar * N + n]);
}

__global__ void tail_copy(const short* __restrict__ src, short* dst, long ld) {
  dst[(long)blockIdx.x * ld + threadIdx.x] = src[blockIdx.x * 64 + threadIdx.x];
}

// per-token rank projection: out[t][a*16+r] = mask * sum_h Abf[t][h]*wa[a][h][r]
template <int KD, int NOUT>
__global__ __launch_bounds__(256)
void lora_proj(const short* __restrict__ Abf, long ldA,
               const float* __restrict__ wa0, const float* __restrict__ wa1,
               const int* __restrict__ seg, short* out0, long ld0, short* out1,
               long ld1) {
  __shared__ __align__(16) short rowbuf[KD];
  __shared__ float part[NOUT][4][16];
  int t = blockIdx.x, tid = threadIdx.x;
  int a = seg[t];
  const int4* src = (const int4*)(Abf + (long)t * ldA);
  for (int c = tid; c < KD / 8; c += 256) ((int4*)rowbuf)[c] = src[c];
  __syncthreads();
  int w = tid >> 6, l = tid & 63;
  int r = l & 15, g = l >> 4;
  const int HW = KD / 4;
  float s0 = 0.f, s1 = 0.f;
  const float* p0 = wa0 + (long)a * KD * 16 + r;
  const float* p1 = (NOUT == 2) ? (wa1 + (long)a * KD * 16 + r) : nullptr;
  int h = w * HW + g;
  for (int k = 0; k < HW / 4; ++k, h += 4) {
    float xv = bf2f(rowbuf[h]);
    s0 = fmaf(xv, p0[(long)h * 16], s0);
    if (NOUT == 2) s1 = fmaf(xv, p1[(long)h * 16], s1);
  }
  s0 += __shfl_xor(s0, 16); s0 += __shfl_xor(s0, 32);
  if (NOUT == 2) { s1 += __shfl_xor(s1, 16); s1 += __shfl_xor(s1, 32); }
  if (l < 16) { part[0][w][r] = s0; if (NOUT == 2) part[1][w][r] = s1; }
  __syncthreads();
  if (tid < 64 * NOUT) {
    int m = tid >> 6, ar = tid & 63;
    float v = 0.f;
    if ((ar >> 4) == a) {
      int r2 = ar & 15;
      v = part[m][0][r2] + part[m][1][r2] + part[m][2][r2] + part[m][3][r2];
    }
    short b = (short)f2bf_bits(v);
    if (m == 0) out0[(long)t * ld0 + ar] = b;
    else        out1[(long)t * ld1 + ar] = b;
  }
}

// ---------------- GEMM: m201-template 8-phase, 2-K-tile double buffer
// C[M][N] = A[M][ldK]@B[N][ldK]^T, LoRA folded as padded K-tail. BM=BN=256,
// BK=64, 512 thr = 8 waves (2M x 4N), per-wave 128x64. LDS 128KB:
// dbuf d (even/odd K-tile) at d*65536: Ah0@0 Ah1@16K Bh0@32K Bh1@48K,
// half-tile = [128 rows][64 cols] bf16. Wave wr reads only Ah(wr); wave wc
// reads only Bh(wc>>1). Per iter (K-tiles u=2i from d0, v=2i+1 from d1),
// 8 phases, each: {quadrant ds_reads; stage 1 half-tile (2 gloads);
// [ph3/ph7: vmcnt(4)]; s_barrier; setprio(1) 16 MFMA setprio(0); s_barrier}.
// Quadrant order per tile: (qm,qn) = (0,0),(0,1),(1,1),(1,0) -> reads
// 12/4/8/0; only 1 aF + 2 bF sets live (64 frag VGPR).
// Stage plan (refill exactly 2 phases after last read of the region):
//   ph0: d1.Ah0 <- tile 2i+1 (read ph4)    ph4: d0.Ah0 <- 2i+2 (read i+1 ph0)
//   ph1: d1.Ah1 <- 2i+1     (read ph6)     ph5: d0.Ah1 <- 2i+2
//   ph2: d0.Bh0 <- 2i+2                    ph6: d1.Bh0 <- 2i+3
//   ph3: d0.Bh1 <- 2i+2                    ph7: d1.Bh1 <- 2i+3
// Wait audit (2 vmem ops/stage/wave, oldest first):
//   at ph3: [ph6',ph7',ph0,ph1,ph2,ph3]=12 -> vmcnt(4) confirms d1.B(v),
//     d1.A(v) (everything ph4-6 reads), leaves [ph2,ph3]=4.
//   at ph7: [ph2..ph7]=12 -> vmcnt(4) confirms all of d0 tile 2i+2
//     (read next iter ph0-2), leaves [ph6,ph7]=4. Never drains mid-loop.
// Last iter (so=false): ph6/ph7 stage nothing; ph7 vmcnt(0) -> tail tile
// NT-1 (the LoRA block; NT odd: 65/173) computed straight-line from d0.
// Swizzle (rule #21): linear gload dest; global chunk c8^(r&7); read chunk
// ((k*4+lhi)^(lrow&7)). Zero bank conflicts (measured R4-R6).
template <int MODE>  // 0: bf16 store; 1: silu(gbuf)*acc -> bf16 in-place; 2: f32
__global__ __launch_bounds__(512, 2)
void gemm8p(const short* __restrict__ A, const short* __restrict__ B,
            const short* gbuf, short* outB, float* outF, int nby, long ldK,
            int NT, long ldo) {
  extern __shared__ __align__(16) char smem[];
  const int D1 = 65536;

  int nwg = gridDim.x;
  int orig = blockIdx.x;
  int q = nwg >> 3, rr = nwg & 7;
  int xcd = orig & 7, loc = orig >> 3;
  int swz = (xcd < rr ? xcd * (q + 1) : rr * (q + 1) + (xcd - rr) * q) + loc;
  int by = swz % nby, bx = swz / nby;   // col fastest: A panel stays in L2
  long row0 = (long)bx * 256, col0 = (long)by * 256;

  int tid = threadIdx.x;
  int l = tid & 63, wid = tid >> 6;
  int wr = wid >> 2, wc = wid & 3;      // 2M x 4N waves, 128x64 each
  int lrow = l & 15, lhi = l >> 4, md = lrow & 7;

  // staging source pointers: chunk idx0=tid (rows 0-63 of half), idx1=idx0+512
  const int rr0 = tid >> 3, cc0 = tid & 7;
  const short* pA0 = A + (row0 + rr0) * ldK + (cc0 ^ (rr0 & 7)) * 8;
  const short* pB0 = B + (col0 + rr0) * ldK + (cc0 ^ (rr0 & 7)) * 8;

  auto stA = [&](int db, int hh, int kt) {
    const short* s = pA0 + (long)hh * 128 * ldK + (long)kt * 64;
    char* d = smem + db + hh * 16384 + tid * 16;
    gload16(s, d);
    gload16(s + 64 * ldK, d + 8192);
  };
  auto stB = [&](int db, int hh, int kt) {
    const short* s = pB0 + (long)hh * 128 * ldK + (long)kt * 64;
    char* d = smem + db + 32768 + hh * 16384 + tid * 16;
    gload16(s, d);
    gload16(s + 64 * ldK, d + 8192);
  };

  f32x4 acc[8][4];
  f32x4 zr = {0.f, 0.f, 0.f, 0.f};
#pragma unroll
  for (int mi = 0; mi < 8; ++mi)
#pragma unroll
    for (int ni = 0; ni < 4; ++ni) acc[mi][ni] = zr;

  bf16x8 aF[4][2], bQ0[2][2], bQ1[2][2];

  auto readA = [&](int db, int qm) {
#pragma unroll
    for (int mi = 0; mi < 4; ++mi) {
      const char* p = smem + db + wr * 16384 + (qm * 64 + mi * 16 + lrow) * 128;
#pragma unroll
      for (int k = 0; k < 2; ++k) {
        FragCast f; f.i = *(const int4*)(p + ((k * 4 + lhi) ^ md) * 16);
        aF[mi][k] = f.b;
      }
    }
  };
  auto readB = [&](int db, int qn, bf16x8 (&bq)[2][2]) {
#pragma unroll
    for (int nj = 0; nj < 2; ++nj) {
      const char* p = smem + db + 32768 + (wc >> 1) * 16384 +
                      ((wc & 1) * 64 + qn * 32 + nj * 16 + lrow) * 128;
#pragma unroll
      for (int k = 0; k < 2; ++k) {
        FragCast f; f.i = *(const int4*)(p + ((k * 4 + lhi) ^ md) * 16);
        bq[nj][k] = f.b;
      }
    }
  };
  auto mfma16 = [&](int qm, int qn, bf16x8 (&bq)[2][2]) {
    __builtin_amdgcn_s_setprio(1);
#pragma unroll
    for (int k = 0; k < 2; ++k)
#pragma unroll
      for (int mi = 0; mi < 4; ++mi)
#pragma unroll
        for (int nj = 0; nj < 2; ++nj)
          acc[qm * 4 + mi][qn * 2 + nj] =
              __builtin_amdgcn_mfma_f32_16x16x32_bf16(
                  aF[mi][k], bq[nj][k], acc[qm * 4 + mi][qn * 2 + nj], 0, 0, 0);
    __builtin_amdgcn_s_setprio(0);
  };

  // prologue: tile 0 full into d0, tile 1's B into d1 (12 ops); confirm
  // tile 0 (8 oldest), leave d1.B (4) in flight = steady-state entry.
  stA(0, 0, 0); stA(0, 1, 0); stB(0, 0, 0); stB(0, 1, 0);
  stB(D1, 0, 1); stB(D1, 1, 1);
  asm volatile("s_waitcnt vmcnt(4)" ::: "memory");
  __builtin_amdgcn_s_barrier();

  const int NI = (NT - 1) >> 1;
#pragma unroll 1
  for (int i = 0; i < NI; ++i) {
    const int t2 = 2 * i;
    const bool so = (t2 + 3) < NT;
    // ph0 — compute u=(t2) quad(0,0); stage d1.Ah0 <- tile t2+1 (JIT)
    readA(0, 0); readB(0, 0, bQ0);
    stA(D1, 0, t2 + 1);
    __builtin_amdgcn_s_barrier();
    mfma16(0, 0, bQ0);
    __builtin_amdgcn_s_barrier();
    // ph1 — quad(0,1); stage d1.Ah1
    readB(0, 1, bQ1);
    stA(D1, 1, t2 + 1);
    __builtin_amdgcn_s_barrier();
    mfma16(0, 1, bQ1);
    __builtin_amdgcn_s_barrier();
    // ph2 — quad(1,1); stage d0.Bh0 <- tile t2+2
    readA(0, 1);
    stB(0, 0, t2 + 2);
    __builtin_amdgcn_s_barrier();
    mfma16(1, 1, bQ1);
    __builtin_amdgcn_s_barrier();
    // ph3 — quad(1,0); stage d0.Bh1; counted wait
    stB(0, 1, t2 + 2);
    asm volatile("s_waitcnt vmcnt(4)" ::: "memory");
    __builtin_amdgcn_s_barrier();
    mfma16(1, 0, bQ0);
    __builtin_amdgcn_s_barrier();
    // ph4 — compute v=(t2+1) quad(0,0); stage d0.Ah0 <- tile t2+2
    readA(D1, 0); readB(D1, 0, bQ0);
    stA(0, 0, t2 + 2);
    __builtin_amdgcn_s_barrier();
    mfma16(0, 0, bQ0);
    __builtin_amdgcn_s_barrier();
    // ph5 — quad(0,1); stage d0.Ah1
    readB(D1, 1, bQ1);
    stA(0, 1, t2 + 2);
    __builtin_amdgcn_s_barrier();
    mfma16(0, 1, bQ1);
    __builtin_amdgcn_s_barrier();
    // ph6 — quad(1,1); stage d1.Bh0 <- tile t2+3 (if it exists)
    readA(D1, 1);
    if (so) stB(D1, 0, t2 + 3);
    __builtin_amdgcn_s_barrier();
    mfma16(1, 1, bQ1);
    __builtin_amdgcn_s_barrier();
    // ph7 — quad(1,0); stage d1.Bh1; counted wait (drain fully if last iter)
    if (so) {
      stB(D1, 1, t2 + 3);
      asm volatile("s_waitcnt vmcnt(4)" ::: "memory");
    } else {
      asm volatile("s_waitcnt vmcnt(0)" ::: "memory");
    }
    __builtin_amdgcn_s_barrier();
    mfma16(1, 0, bQ0);
    __builtin_amdgcn_s_barrier();
  }

  // tail: tile NT-1 (the LoRA augmented block) from d0, straight-line
  readA(0, 0); readB(0, 0, bQ0); readB(0, 1, bQ1);
  mfma16(0, 0, bQ0);
  mfma16(0, 1, bQ1);
  readA(0, 1);
  mfma16(1, 1, bQ1);
  mfma16(1, 0, bQ0);

  // epilogue: C/D layout col=lane&15, row=(lane>>4)*4+reg  [m89]
  // acc[mi] rows: (mi>>2)*64 + (mi&3)*16; acc[.][ni] cols: ni*16
#pragma unroll
  for (int mi = 0; mi < 8; ++mi)
#pragma unroll
    for (int ni = 0; ni < 4; ++ni)
#pragma unroll
      for (int j = 0; j < 4; ++j) {
        long grow = row0 + wr * 128 + (mi >> 2) * 64 + (mi & 3) * 16 +
                    lhi * 4 + j;
        long gcol = col0 + wc * 64 + ni * 16 + lrow;
        long idx = grow * ldo + gcol;
        float v = acc[mi][ni][j];
        if constexpr (MODE == 0) {
          outB[idx] = (short)f2bf_bits(v);
        } else if constexpr (MODE == 1) {
          float g = bf2f(gbuf[idx]);
          float t2 = g * (1.f / (1.f + __expf(-g))) * v;   // silu(g)*u
          outB[idx] = (short)f2bf_bits(t2);
        } else {
          outF[idx] = v;
        }
      }
}

// ---------------------------------------------------------------- launcher
extern "C" void kernel_launch(void* const* d_in, const int* in_sizes, int n_in,
                              void* d_out, int out_size, void* d_ws,
                              size_t ws_size, hipStream_t stream) {
  const float* x       = (const float*)d_in[0];
  const float* gate_w  = (const float*)d_in[1];
  const float* up_w    = (const float*)d_in[2];
  const float* down_w  = (const float*)d_in[3];
  const float* gate_wa = (const float*)d_in[4];
  const float* gate_wb = (const float*)d_in[5];
  const float* up_wa   = (const float*)d_in[6];
  const float* up_wb   = (const float*)d_in[7];
  const float* down_wa = (const float*)d_in[8];
  const float* down_wb = (const float*)d_in[9];
  const int*   seg     = (const int*)d_in[10];

  char* ws = (char*)d_ws;
  short* xg_pad = (short*)(ws);                   // [4096][4160]  34.1 MB
  short* wA     = (short*)(ws + 34078720);        // gate_w pad -> down_w pad
  short* wB     = (short*)(ws + 125665280);       // up_w pad      91.6 MB
  short* t_pad  = (short*)(ws + 217251840);       // [4096][11072] 90.7 MB
  short* xa_u   = (short*)(ws + 307953664);       // [4096][64]

  const int LDS_BYTES = 131072;   // 2 dbuf x (A 32KB + B 32KB)
  hipFuncSetAttribute(reinterpret_cast<const void*>(&gemm8p<0>),
                      hipFuncAttributeMaxDynamicSharedMemorySize, LDS_BYTES);
  hipFuncSetAttribute(reinterpret_cast<const void*>(&gemm8p<1>),
                      hipFuncAttributeMaxDynamicSharedMemorySize, LDS_BYTES);
  hipFuncSetAttribute(reinterpret_cast<const void*>(&gemm8p<2>),
                      hipFuncAttributeMaxDynamicSharedMemorySize, LDS_BYTES);

  // bf16 padded operand build
  cvt_pad<<<T_TOK, 256, 0, stream>>>(x, xg_pad, 512, HID, 4160);
  cvt_pad<<<IMD, 256, 0, stream>>>(gate_w, wA, 512, HID, 4160);
  cvt_pad<<<IMD, 256, 0, stream>>>(up_w, wB, 512, HID, 4160);
  build_wbT_pad<<<dim3(43, 64), 256, 0, stream>>>(gate_wb, wA, IMD, 4160, HID);
  build_wbT_pad<<<dim3(43, 64), 256, 0, stream>>>(up_wb, wB, IMD, 4160, HID);
  lora_proj<HID, 2><<<T_TOK, 256, 0, stream>>>(
      xg_pad, 4160, gate_wa, up_wa, seg, xg_pad + HID, 4160, xa_u, 64);

  // gate: t_pad = x @ gate_w^T + lora        [M=4096, N=11008, K'=4160 -> NT=65]
  gemm8p<0><<<16 * 43, 512, LDS_BYTES, stream>>>(
      xg_pad, wA, nullptr, t_pad, nullptr, 43, 4160, 65, 11072);
  // swap LoRA tail to up's xa, then up+silu fuse (in place over t_pad)
  tail_copy<<<T_TOK, 64, 0, stream>>>(xa_u, xg_pad + HID, 4160);
  gemm8p<1><<<16 * 43, 512, LDS_BYTES, stream>>>(
      xg_pad, wB, t_pad, t_pad, nullptr, 43, 4160, 65, 11072);

  // down operand build (wA region is free after gate GEMM)
  cvt_pad<<<T_TOK, 256, 0, stream>>>(down_w, wA, 1376, IMD, 11072);
  build_wbT_pad<<<dim3(16, 64), 256, 0, stream>>>(down_wb, wA, HID, 11072, IMD);
  lora_proj<IMD, 1><<<T_TOK, 256, 0, stream>>>(
      t_pad, 11072, down_wa, nullptr, seg, t_pad + IMD, 11072, nullptr, 64);

  // down: out = t @ down_w^T + lora          [M=4096, N=4096, K'=11072 -> NT=173]
  gemm8p<2><<<16 * 16, 512, LDS_BYTES, stream>>>(
      t_pad, wA, nullptr, nullptr, (float*)d_out, 16, 11072, 173, 4096);
}